// Round 7
// baseline (103.994 us; speedup 1.0000x reference)
//
#include <hip/hip_runtime.h>
#include <stdint.h>

// Problem constants
#define NB    32768
#define SS    11
#define DD    128
#define HH    32
#define ROWS  (NB * SS)        // 360448
#define RPB   128              // rows per tile
#define TILES (ROWS / RPB)     // 2816
#define GBLK  768              // persistent blocks (3/CU), grid-stride over tiles
#define TPB   256              // threads per block (4 waves)
#define XSTRD 68               // dwords per LDS x row (64 data + 4 pad)
#define TOT4  (ROWS * SS / 4)  // 991232 float4 of attn ones
#define AUXOFF (ROWS * 2)      // float offset of aux region in scratch

__device__ __forceinline__ uint32_t f2bf_u(float f) {
    uint32_t u = __float_as_uint(f);
    return (u + 0x7fffu + ((u >> 16) & 1u)) >> 16;   // RNE
}
__device__ __forceinline__ uint32_t pkbf(float lo, float hi) {
    return f2bf_u(lo) | (f2bf_u(hi) << 16);
}
// D = a.bf16[0]*b.bf16[0] + a.bf16[1]*b.bf16[1] + c  (one VALU op)
__device__ __forceinline__ float dot2bf(uint32_t a, uint32_t b, float c) {
    float d;
    asm("v_dot2_f32_bf16 %0, %1, %2, %3" : "=v"(d) : "v"(a), "v"(b), "v"(c));
    return d;
}
// returns v[lane] + v[lane^32], VALU-only (any half-exchange semantic works)
__device__ __forceinline__ float xor32sum(float v) {
    float a = v, b = v;
    asm("v_permlane32_swap_b32 %0, %1" : "+v"(a), "+v"(b));
    return a + b;
}

// One block, 64 threads. aux[0..64) = M = Wv@Wo (layout [j][o]);
// aux[64..86) = posW[t][o] = bo[o] + sum_{u in win(t)} (pos[u] @ M)[o]
__global__ __launch_bounds__(64) void setup_kernel(
    const float* __restrict__ Wv, const float* __restrict__ Wo,
    const float* __restrict__ pos, const float* __restrict__ bo,
    float* __restrict__ aux)
{
    __shared__ float M_s[HH * 2];
    __shared__ float pm_s[SS * 2];
    const int t = threadIdx.x;
    {
        int j = t >> 1, o = t & 1;
        float s = 0.f;
        #pragma unroll 8
        for (int k = 0; k < HH; ++k) s += Wv[j * HH + k] * Wo[k * 2 + o];
        M_s[t] = s;
        aux[t] = s;
    }
    __syncthreads();
    if (t < 2 * SS) {
        int u = t >> 1, o = t & 1;
        float s = 0.f;
        #pragma unroll 8
        for (int j = 0; j < HH; ++j) s += pos[u * HH + j] * M_s[j * 2 + o];
        pm_s[t] = s;
    }
    __syncthreads();
    if (t < 2 * SS) {
        int tt = t >> 1, o = t & 1;
        int lo = tt - 5 < 0 ? 0 : tt - 5;
        int hi = tt + 5 > SS - 1 ? SS - 1 : tt + 5;
        float s = bo[o];
        for (int u = lo; u <= hi; ++u) s += pm_s[u * 2 + o];
        aux[64 + t] = s;
    }
}

// g[r,o] = ( relu(x_r @ W1 + b1) @ M )[o]   (pos/bias terms live in posW)
// Persistent blocks; per tile: prefetch next tile's x into regs (T14),
// compute current tile from LDS, then pack+write after the barrier.
__global__ __launch_bounds__(TPB, 3) void g_kernel(
    const float* __restrict__ x, const float* __restrict__ W1,
    const float* __restrict__ b1, const float* __restrict__ aux,
    float* __restrict__ g)
{
    __shared__ uint32_t x_p[RPB * XSTRD];   // 34816 B (bf16-pair packed x)
    __shared__ uint32_t w_p[64 * HH];       //  8192 B (w_p[p][j] = {W1[2p][j],W1[2p+1][j]})

    const int t = threadIdx.x;
    const int blk = blockIdx.x;

    const int lane = t & 63, wave = t >> 6;
    const int cg = lane & 3;           // cols j0..j0+7
    const int rg = (lane >> 2) & 7;    // rows rbase+8rr
    const int kc = lane >> 5;          // pairs kc*32..+31
    const int j0 = cg * 8;
    const int rbase = wave * 32 + rg;

    // per-thread constants (global, L1-hot)
    float b1v[8], Mv[16];
    *(float4*)&b1v[0] = *(const float4*)&b1[j0];
    *(float4*)&b1v[4] = *(const float4*)&b1[j0 + 4];
    #pragma unroll
    for (int q = 0; q < 4; ++q)
        *(float4*)&Mv[q * 4] = *(const float4*)&aux[j0 * 2 + q * 4];

    // ---- stage W1 once per block (persistent) ----
    #pragma unroll
    for (int k = 0; k < 8; ++k) {
        int i = t + k * TPB;               // [0, 2048)
        int p = i >> 5, j = i & 31;
        w_p[i] = pkbf(W1[(2 * p) * HH + j], W1[(2 * p + 1) * HH + j]);
    }

    // ---- prologue: load + write tile0 ----
    int tile = blk;
    float4 xr[16];
    {
        const float4* xs = (const float4*)(x + (size_t)tile * (RPB * DD));
        #pragma unroll
        for (int k = 0; k < 8; ++k) {
            int j = t + k * TPB;
            xr[2 * k]     = xs[2 * j];
            xr[2 * k + 1] = xs[2 * j + 1];
        }
    }
    #pragma unroll
    for (int k = 0; k < 8; ++k) {
        int j = t + k * TPB;
        uint4 pv;
        pv.x = pkbf(xr[2 * k].x, xr[2 * k].y);
        pv.y = pkbf(xr[2 * k].z, xr[2 * k].w);
        pv.z = pkbf(xr[2 * k + 1].x, xr[2 * k + 1].y);
        pv.w = pkbf(xr[2 * k + 1].z, xr[2 * k + 1].w);
        int row = j >> 4, d8 = j & 15;
        *(uint4*)&x_p[row * XSTRD + d8 * 4] = pv;
    }
    __syncthreads();

    for (;;) {
        const int next = tile + GBLK;
        // ---- issue next tile's loads early (hidden under compute) ----
        if (next < TILES) {
            const float4* xs = (const float4*)(x + (size_t)next * (RPB * DD));
            #pragma unroll
            for (int k = 0; k < 8; ++k) {
                int j = t + k * TPB;
                xr[2 * k]     = xs[2 * j];
                xr[2 * k + 1] = xs[2 * j + 1];
            }
        }

        // ---- compute tile: 4 rows x 8 cols x 32 pairs per thread ----
        // x-read banks: 4rg quads, kc 2-way (free), cg bcast -> conflict-free
        // w-read banks: 8cg+4q distinct quads, rg bcast      -> conflict-free
        float acc[4][8] = {};
        #pragma unroll
        for (int i = 0; i < 8; ++i) {
            uint32_t xv[4][4];
            #pragma unroll
            for (int rr = 0; rr < 4; ++rr)
                *(uint4*)xv[rr] =
                    *(const uint4*)&x_p[(rbase + 8 * rr) * XSTRD + kc * 32 + i * 4];
            #pragma unroll
            for (int pp = 0; pp < 4; ++pp) {
                uint32_t wv[8];
                *(uint4*)&wv[0] = *(const uint4*)&w_p[(kc * 32 + i * 4 + pp) * HH + j0];
                *(uint4*)&wv[4] = *(const uint4*)&w_p[(kc * 32 + i * 4 + pp) * HH + j0 + 4];
                #pragma unroll
                for (int rr = 0; rr < 4; ++rr)
                    #pragma unroll
                    for (int c = 0; c < 8; ++c)
                        acc[rr][c] = dot2bf(xv[rr][pp], wv[c], acc[rr][c]);
            }
        }

        // ---- epilogue: kc-sum -> relu(+b1) -> @M -> cg-reduce -> store ----
        #pragma unroll
        for (int rr = 0; rr < 4; ++rr) {
            float s0 = 0.f, s1 = 0.f;
            #pragma unroll
            for (int c = 0; c < 8; ++c) {
                float full = xor32sum(acc[rr][c]);     // sum over kc halves
                float y = fmaxf(full + b1v[c], 0.f);
                s0 = fmaf(y, Mv[c * 2], s0);
                s1 = fmaf(y, Mv[c * 2 + 1], s1);
            }
            s0 += __shfl_xor(s0, 1); s1 += __shfl_xor(s1, 1);
            s0 += __shfl_xor(s0, 2); s1 += __shfl_xor(s1, 2);
            if ((lane & 35) == 0) {        // cg==0 && kc==0
                int row = tile * RPB + rbase + 8 * rr;
                ((float2*)g)[row] = make_float2(s0, s1);
            }
        }

        if (next >= TILES) break;
        __syncthreads();                   // all waves done reading x_p
        // ---- pack + write next tile (implicit vmcnt wait, post-compute) ----
        #pragma unroll
        for (int k = 0; k < 8; ++k) {
            int j = t + k * TPB;
            uint4 pv;
            pv.x = pkbf(xr[2 * k].x, xr[2 * k].y);
            pv.y = pkbf(xr[2 * k].z, xr[2 * k].w);
            pv.z = pkbf(xr[2 * k + 1].x, xr[2 * k + 1].y);
            pv.w = pkbf(xr[2 * k + 1].z, xr[2 * k + 1].w);
            int row = j >> 4, d8 = j & 15;
            *(uint4*)&x_p[row * XSTRD + d8 * 4] = pv;
        }
        __syncthreads();                   // writes visible
        tile = next;
    }
}

// merged: attn ones fill + out1 window sum (ws_ok path only)
__global__ __launch_bounds__(256) void outones_kernel(
    const float* __restrict__ g, const float* __restrict__ aux,
    float* __restrict__ out1, float4* __restrict__ attn)
{
    int idx = blockIdx.x * 256 + threadIdx.x;       // [0, TOT4)
    attn[idx] = make_float4(1.f, 1.f, 1.f, 1.f);
    if (idx < ROWS) {
        int b = idx / SS, tt = idx - b * SS;
        const float2* gb = (const float2*)(g + (size_t)b * (2 * SS));
        int lo = tt - 5 < 0 ? 0 : tt - 5;
        int hi = tt + 5 > SS - 1 ? SS - 1 : tt + 5;
        float2 pw = *(const float2*)&aux[64 + tt * 2];
        float s0 = pw.x, s1 = pw.y;
        for (int u = lo; u <= hi; ++u) { float2 v = gb[u]; s0 += v.x; s1 += v.y; }
        ((float2*)out1)[idx] = make_float2(s0, s1);
    }
}

// fallback-only pair (g aliased into attn region: must read g before ones)
__global__ __launch_bounds__(256) void out_kernel(
    const float* __restrict__ g, const float* __restrict__ aux,
    float* __restrict__ out1)
{
    int idx = blockIdx.x * 256 + threadIdx.x;
    int b = idx / SS, tt = idx - b * SS;
    const float2* gb = (const float2*)(g + (size_t)b * (2 * SS));
    int lo = tt - 5 < 0 ? 0 : tt - 5;
    int hi = tt + 5 > SS - 1 ? SS - 1 : tt + 5;
    float2 pw = *(const float2*)&aux[64 + tt * 2];
    float s0 = pw.x, s1 = pw.y;
    for (int u = lo; u <= hi; ++u) { float2 v = gb[u]; s0 += v.x; s1 += v.y; }
    ((float2*)out1)[idx] = make_float2(s0, s1);
}
__global__ __launch_bounds__(256) void ones_kernel(float4* __restrict__ p)
{
    int i = blockIdx.x * 256 + threadIdx.x;
    p[i] = make_float4(1.f, 1.f, 1.f, 1.f);
}

extern "C" void kernel_launch(void* const* d_in, const int* in_sizes, int n_in,
                              void* d_out, int out_size, void* d_ws, size_t ws_size,
                              hipStream_t stream)
{
    const float* x   = (const float*)d_in[0];
    const float* W1  = (const float*)d_in[1];
    const float* b1  = (const float*)d_in[2];
    // d_in[3] = Wq, d_in[4] = Wk: dead (softmax over singleton dim -> attn_w == 1)
    const float* Wv  = (const float*)d_in[5];
    const float* pos = (const float*)d_in[6];
    const float* Wo  = (const float*)d_in[7];
    const float* bo  = (const float*)d_in[8];

    float* out1 = (float*)d_out;                 // (B,S,2)
    float* attn = out1 + (size_t)ROWS * 2;       // (B,S,1,11)

    const bool ws_ok = ws_size >= (size_t)(AUXOFF + 128) * sizeof(float);
    float* base = ws_ok ? (float*)d_ws : attn;   // fallback: reuse attn region
    float* g    = base;                          // ROWS*2 floats
    float* aux  = base + AUXOFF;                 // 86 floats (M + posW)

    setup_kernel<<<1, 64, 0, stream>>>(Wv, Wo, pos, bo, aux);
    g_kernel<<<GBLK, TPB, 0, stream>>>(x, W1, b1, aux, g);
    if (ws_ok) {
        outones_kernel<<<TOT4 / 256, 256, 0, stream>>>(g, aux, out1, (float4*)attn);
    } else {
        out_kernel<<<ROWS / 256, 256, 0, stream>>>(g, aux, out1);
        ones_kernel<<<TOT4 / 256, 256, 0, stream>>>((float4*)attn);
    }
}

// Round 9
// 55.513 us; speedup vs baseline: 1.8733x; 1.8733x over previous
//
#include <hip/hip_runtime.h>
#include <stdint.h>

// Problem constants
#define NB    32768
#define SS    11
#define DD    128
#define HH    32
#define ROWS  (NB * SS)        // 360448
#define RPB   256              // rows per tile/block
#define NBLK  (ROWS / RPB)     // 1408
#define TPB   512              // threads per block (8 waves)
#define XSTRD 68               // dwords per LDS x row (64 data + 4 pad)
#define TOT4  (ROWS * SS / 4)  // 991232 float4 of attn ones
#define AUXOFF (ROWS * 2)      // float offset of aux region in scratch

// pack two f32 -> dword of 2x bf16 (RNE), single VALU op
__device__ __forceinline__ uint32_t pkbf(float lo, float hi) {
    uint32_t r;
    asm("v_cvt_pk_bf16_f32 %0, %1, %2" : "=v"(r) : "v"(lo), "v"(hi));
    return r;
}
// D = a.bf16[0]*b.bf16[0] + a.bf16[1]*b.bf16[1] + c  (one VALU op)
__device__ __forceinline__ float dot2bf(uint32_t a, uint32_t b, float c) {
    float d;
    asm("v_dot2_f32_bf16 %0, %1, %2, %3" : "=v"(d) : "v"(a), "v"(b), "v"(c));
    return d;
}
// returns v[lane] + v[lane^32], VALU-only (any half-exchange semantic works)
__device__ __forceinline__ float xor32sum(float v) {
    float a = v, b = v;
    asm("v_permlane32_swap_b32 %0, %1" : "+v"(a), "+v"(b));
    return a + b;
}

// One block, 256 threads. aux[0..64) = M = Wv@Wo (layout [j][o]);
// aux[64..86) = posW[t][o] = bo[o] + sum_{u in win(t)} (pos[u] @ M)[o]
__global__ __launch_bounds__(256) void setup_kernel(
    const float* __restrict__ Wv, const float* __restrict__ Wo,
    const float* __restrict__ pos, const float* __restrict__ bo,
    float* __restrict__ aux)
{
    __shared__ float M_s[HH * 2];
    __shared__ float pm_s[SS * 2];
    const int t = threadIdx.x;
    {   // thread (j, o, kq): 4-way k-split, shfl-reduce over kq (lane bits 0-1)
        int i2 = t >> 2, kq = t & 3;       // i2 = j*2+o in [0,64), kq k-quarter
        int j = i2 >> 1, o = i2 & 1;
        float s = 0.f;
        #pragma unroll
        for (int k = kq * 8; k < kq * 8 + 8; ++k)
            s += Wv[j * HH + k] * Wo[k * 2 + o];
        s += __shfl_xor(s, 1);
        s += __shfl_xor(s, 2);
        if (kq == 0) { M_s[i2] = s; aux[i2] = s; }
    }
    __syncthreads();
    if (t < 2 * SS) {
        int u = t >> 1, o = t & 1;
        float s = 0.f;
        #pragma unroll 8
        for (int j = 0; j < HH; ++j) s += pos[u * HH + j] * M_s[j * 2 + o];
        pm_s[t] = s;
    }
    __syncthreads();
    if (t < 2 * SS) {
        int tt = t >> 1, o = t & 1;
        int lo = tt - 5 < 0 ? 0 : tt - 5;
        int hi = tt + 5 > SS - 1 ? SS - 1 : tt + 5;
        float s = bo[o];
        for (int u = lo; u <= hi; ++u) s += pm_s[u * 2 + o];
        aux[64 + t] = s;
    }
}

// g[r,o] = ( relu(x_r @ W1 + b1) @ M )[o]   (pos/bias terms live in posW)
// R6-verified math; 256-row tile + 8 waves -> 2 blocks/CU, 16 waves/CU (50%).
__global__ __launch_bounds__(TPB, 2) void g_kernel(
    const float* __restrict__ x, const float* __restrict__ W1,
    const float* __restrict__ b1, const float* __restrict__ aux,
    float* __restrict__ g)
{
    __shared__ uint32_t x_p[RPB * XSTRD];   // 69632 B (bf16-pair packed x)
    __shared__ uint32_t w_p[64 * HH];       //  8192 B (w_p[p][j]={W1[2p][j],W1[2p+1][j]})

    const int t   = threadIdx.x;
    const int blk = blockIdx.x;

    // ---- stage x tile (256 rows x 128 f32): 8 floats -> uint4 -> b128 write ----
    const float4* xsrc = (const float4*)(x + (size_t)blk * (RPB * DD));
    #pragma unroll
    for (int k = 0; k < 8; ++k) {
        int j = t + k * TPB;               // [0, 4096)
        float4 v0 = xsrc[2 * j], v1 = xsrc[2 * j + 1];
        uint4 pv;
        pv.x = pkbf(v0.x, v0.y); pv.y = pkbf(v0.z, v0.w);
        pv.z = pkbf(v1.x, v1.y); pv.w = pkbf(v1.z, v1.w);
        int row = j >> 4, d8 = j & 15;     // 16 uint4 per row
        *(uint4*)&x_p[row * XSTRD + d8 * 4] = pv;
    }
    // ---- stage W1 as packed bf16 d-pairs ----
    #pragma unroll
    for (int k = 0; k < 4; ++k) {
        int i = t + k * TPB;               // [0, 2048)
        int p = i >> 5, j = i & 31;
        w_p[i] = pkbf(W1[(2 * p) * HH + j], W1[(2 * p + 1) * HH + j]);
    }

    const int lane = t & 63, wave = t >> 6;    // wave in [0,8)
    const int cg = lane & 3;           // cols j0..j0+7
    const int rg = (lane >> 2) & 7;    // rows rbase+8rr
    const int kc = lane >> 5;          // pairs kc*32..+31
    const int j0 = cg * 8;
    const int rbase = wave * 32 + rg;  // [0, 256)

    // per-thread constants (global, L1-hot; independent of LDS)
    float b1v[8], Mv[16];
    *(float4*)&b1v[0] = *(const float4*)&b1[j0];
    *(float4*)&b1v[4] = *(const float4*)&b1[j0 + 4];
    #pragma unroll
    for (int q = 0; q < 4; ++q)
        *(float4*)&Mv[q * 4] = *(const float4*)&aux[j0 * 2 + q * 4];
    __syncthreads();

    // ---- compute: 4 rows x 8 cols x 32 pairs per thread ----
    // x-read banks: 4rg quads, kc 2-way same-bank-diff-addr (free), cg bcast
    // w-read banks: j%32 = 8cg+[0..7] covers all banks, rg bcast, kc 2-way
    float acc[4][8] = {};
    #pragma unroll
    for (int i = 0; i < 8; ++i) {          // 4 d-pairs per iter
        uint32_t xv[4][4];
        #pragma unroll
        for (int rr = 0; rr < 4; ++rr)
            *(uint4*)xv[rr] =
                *(const uint4*)&x_p[(rbase + 8 * rr) * XSTRD + kc * 32 + i * 4];
        #pragma unroll
        for (int pp = 0; pp < 4; ++pp) {
            uint32_t wv[8];
            *(uint4*)&wv[0] = *(const uint4*)&w_p[(kc * 32 + i * 4 + pp) * HH + j0];
            *(uint4*)&wv[4] = *(const uint4*)&w_p[(kc * 32 + i * 4 + pp) * HH + j0 + 4];
            #pragma unroll
            for (int rr = 0; rr < 4; ++rr)
                #pragma unroll
                for (int c = 0; c < 8; ++c)
                    acc[rr][c] = dot2bf(xv[rr][pp], wv[c], acc[rr][c]);
        }
    }

    // ---- epilogue: kc-sum (VALU) -> relu(+b1) -> @M -> cg-reduce -> store ----
    #pragma unroll
    for (int rr = 0; rr < 4; ++rr) {
        float s0 = 0.f, s1 = 0.f;
        #pragma unroll
        for (int c = 0; c < 8; ++c) {
            float full = xor32sum(acc[rr][c]);     // sum over kc halves
            float y = fmaxf(full + b1v[c], 0.f);
            s0 = fmaf(y, Mv[c * 2], s0);
            s1 = fmaf(y, Mv[c * 2 + 1], s1);
        }
        s0 += __shfl_xor(s0, 1); s1 += __shfl_xor(s1, 1);
        s0 += __shfl_xor(s0, 2); s1 += __shfl_xor(s1, 2);
        if ((lane & 35) == 0) {            // cg==0 && kc==0
            int row = blk * RPB + rbase + 8 * rr;
            ((float2*)g)[row] = make_float2(s0, s1);
        }
    }
}

// merged: attn ones fill + out1 window sum (ws_ok path only)
__global__ __launch_bounds__(256) void outones_kernel(
    const float* __restrict__ g, const float* __restrict__ aux,
    float* __restrict__ out1, float4* __restrict__ attn)
{
    int idx = blockIdx.x * 256 + threadIdx.x;       // [0, TOT4)
    attn[idx] = make_float4(1.f, 1.f, 1.f, 1.f);
    if (idx < ROWS) {
        int b = idx / SS, tt = idx - b * SS;
        const float2* gb = (const float2*)(g + (size_t)b * (2 * SS));
        int lo = tt - 5 < 0 ? 0 : tt - 5;
        int hi = tt + 5 > SS - 1 ? SS - 1 : tt + 5;
        float2 pw = *(const float2*)&aux[64 + tt * 2];
        float s0 = pw.x, s1 = pw.y;
        for (int u = lo; u <= hi; ++u) { float2 v = gb[u]; s0 += v.x; s1 += v.y; }
        ((float2*)out1)[idx] = make_float2(s0, s1);
    }
}

// fallback-only pair (g aliased into attn region: must read g before ones)
__global__ __launch_bounds__(256) void out_kernel(
    const float* __restrict__ g, const float* __restrict__ aux,
    float* __restrict__ out1)
{
    int idx = blockIdx.x * 256 + threadIdx.x;
    int b = idx / SS, tt = idx - b * SS;
    const float2* gb = (const float2*)(g + (size_t)b * (2 * SS));
    int lo = tt - 5 < 0 ? 0 : tt - 5;
    int hi = tt + 5 > SS - 1 ? SS - 1 : tt + 5;
    float2 pw = *(const float2*)&aux[64 + tt * 2];
    float s0 = pw.x, s1 = pw.y;
    for (int u = lo; u <= hi; ++u) { float2 v = gb[u]; s0 += v.x; s1 += v.y; }
    ((float2*)out1)[idx] = make_float2(s0, s1);
}
__global__ __launch_bounds__(256) void ones_kernel(float4* __restrict__ p)
{
    int i = blockIdx.x * 256 + threadIdx.x;
    p[i] = make_float4(1.f, 1.f, 1.f, 1.f);
}

extern "C" void kernel_launch(void* const* d_in, const int* in_sizes, int n_in,
                              void* d_out, int out_size, void* d_ws, size_t ws_size,
                              hipStream_t stream)
{
    const float* x   = (const float*)d_in[0];
    const float* W1  = (const float*)d_in[1];
    const float* b1  = (const float*)d_in[2];
    // d_in[3] = Wq, d_in[4] = Wk: dead (softmax over singleton dim -> attn_w == 1)
    const float* Wv  = (const float*)d_in[5];
    const float* pos = (const float*)d_in[6];
    const float* Wo  = (const float*)d_in[7];
    const float* bo  = (const float*)d_in[8];

    float* out1 = (float*)d_out;                 // (B,S,2)
    float* attn = out1 + (size_t)ROWS * 2;       // (B,S,1,11)

    const bool ws_ok = ws_size >= (size_t)(AUXOFF + 128) * sizeof(float);
    float* base = ws_ok ? (float*)d_ws : attn;   // fallback: reuse attn region
    float* g    = base;                          // ROWS*2 floats
    float* aux  = base + AUXOFF;                 // 86 floats (M + posW)

    setup_kernel<<<1, 256, 0, stream>>>(Wv, Wo, pos, bo, aux);
    g_kernel<<<NBLK, TPB, 0, stream>>>(x, W1, b1, aux, g);
    if (ws_ok) {
        outones_kernel<<<TOT4 / 256, 256, 0, stream>>>(g, aux, out1, (float4*)attn);
    } else {
        out_kernel<<<ROWS / 256, 256, 0, stream>>>(g, aux, out1);
        ones_kernel<<<TOT4 / 256, 256, 0, stream>>>((float4*)attn);
    }
}